// Round 13
// baseline (25.643 us; speedup 1.0000x reference)
//
#include <hip/hip_runtime.h>
#include <math.h>

#define B_SZ 2
#define T_SZ 512
#define D_SZ 64
#define ELEMS 4096            // D*D

// K2 geometry: 512 blocks = (b, r, col-quarter). 256 threads = 64 chunks x 4
// float4 col-groups. CLEN2=8 timesteps per chunk. Hierarchical carry fold:
// 8 groups of 8 chunks (depth <=7 + depth <=7). ~2 blocks/CU for overlap.
#define NCH2 64
#define CLEN2 8               // NCH2*CLEN2 == T_SZ
#define NCG  4                // col-groups per block (4 x float4 = 16 cols)

// ws layout: decay_t [B][D][T] at 0 (256 KB); M=mu*rs [B*T]; R=rs [B*T]
#define DECAY_BYTES ((size_t)B_SZ * D_SZ * T_SZ * 4)
#define M_OFF   DECAY_BYTES
#define R_OFF   (DECAY_BYTES + (size_t)B_SZ * T_SZ * 4)

// Kernel 1 (proven): per-(b,t) LN stats + row-dot + decay.
__global__ __launch_bounds__(256) void ln_dt_kernel(
    const float* __restrict__ x, const float* __restrict__ log_A,
    const float* __restrict__ dt_w, const float* __restrict__ dt_b,
    const float* __restrict__ ln_w, const float* __restrict__ ln_b,
    float* __restrict__ decay_t, float* __restrict__ Mst, float* __restrict__ Rst)
{
    const int bt  = blockIdx.x;
    const int tid = threadIdx.x;
    const size_t base = (size_t)bt * ELEMS;

    float4 v[4];
    float sum = 0.f, sumsq = 0.f;
    const float4* xv4 = reinterpret_cast<const float4*>(x + base);
#pragma unroll
    for (int k = 0; k < 4; ++k) {
        v[k] = xv4[tid + 256 * k];
        sum   += v[k].x + v[k].y + v[k].z + v[k].w;
        sumsq += v[k].x * v[k].x + v[k].y * v[k].y + v[k].z * v[k].z + v[k].w * v[k].w;
    }

    __shared__ float red0[4], red1[4];
#pragma unroll
    for (int off = 32; off; off >>= 1) {
        sum   += __shfl_down(sum, off);
        sumsq += __shfl_down(sumsq, off);
    }
    const int wave = tid >> 6;
    if ((tid & 63) == 0) { red0[wave] = sum; red1[wave] = sumsq; }
    __syncthreads();
    sum   = red0[0] + red0[1] + red0[2] + red0[3];
    sumsq = red1[0] + red1[1] + red1[2] + red1[3];

    const float mu = sum * (1.f / ELEMS);
    const float var = sumsq * (1.f / ELEMS) - mu * mu;
    const float rs = rsqrtf(var + 1e-5f);

    const float4* w4p = reinterpret_cast<const float4*>(ln_w);
    const float4* b4p = reinterpret_cast<const float4*>(ln_b);
    const float4* dw4 = reinterpret_cast<const float4*>(dt_w);
    float dot[4] = {0.f, 0.f, 0.f, 0.f};
#pragma unroll
    for (int k = 0; k < 4; ++k) {
        const int f = tid + 256 * k;
        float4 w4 = w4p[f];
        float4 b4 = b4p[f];
        float4 xn;
        xn.x = (v[k].x - mu) * rs * w4.x + b4.x;
        xn.y = (v[k].y - mu) * rs * w4.y + b4.y;
        xn.z = (v[k].z - mu) * rs * w4.z + b4.z;
        xn.w = (v[k].w - mu) * rs * w4.w + b4.w;
        float4 wv = dw4[f & 15];
        dot[k] += xn.x * wv.x + xn.y * wv.y + xn.z * wv.z + xn.w * wv.w;
    }

#pragma unroll
    for (int m = 1; m <= 8; m <<= 1) {
#pragma unroll
        for (int k = 0; k < 4; ++k) dot[k] += __shfl_xor(dot[k], m);
    }

    if (tid == 0) { Mst[bt] = mu * rs; Rst[bt] = rs; }

    if ((tid & 15) == 0) {
        const int m = tid >> 4;
        const float db = dt_b[0];
        const int b = bt >> 9;
        const int t = bt & (T_SZ - 1);
#pragma unroll
        for (int k = 0; k < 4; ++k) {
            const int r = m + 16 * k;
            const float z = dot[k] + db;
            const float dt = (z > 20.f) ? z : log1pf(expf(z));
            const float A = -expf(log_A[r]);
            decay_t[((size_t)(b * D_SZ + r)) * T_SZ + t] = expf(dt * A);
        }
    }
}

// Kernel 2: block = (b, r, col-quarter). 512 blocks x 256 threads (~2/CU).
// Thread (chunk k, cg) owns float4; loads issued up-front, decays kept in
// registers, local scan, two-level hierarchical fold, apply, write.
__global__ __launch_bounds__(256, 2) void scan_hfold_kernel(
    const float* __restrict__ x,
    const float* __restrict__ Mst, const float* __restrict__ Rst,
    const float* __restrict__ decay_t,
    const float* __restrict__ ln_w, const float* __restrict__ ln_b,
    float* __restrict__ out)
{
    const int tid = threadIdx.x;
    const int cg  = tid & (NCG - 1);      // 0..3
    const int k   = tid >> 2;             // chunk 0..63
    const int cq  = blockIdx.x & 3;       // col-quarter
    const int row = blockIdx.x >> 2;      // (b*64 + r)
    const int b   = row >> 6;
    const int r   = row & 63;
    const int t0  = k * CLEN2;
    const int c0  = cq * 16 + cg * 4;

    __shared__ float  sd[T_SZ];
    __shared__ float  sM[T_SZ];
    __shared__ float  sR[T_SZ];
    __shared__ float4 sS[NCH2][NCG];
    __shared__ float  sP[NCH2];
    __shared__ float4 sGS[8][NCG];
    __shared__ float  sGP[8];

    // issue x tile loads first (independent of staging)
    const float* xp = x + ((size_t)(b * T_SZ + t0) * D_SZ + r) * D_SZ + c0;
    float4 xv[CLEN2];
#pragma unroll
    for (int i = 0; i < CLEN2; ++i)
        xv[i] = *reinterpret_cast<const float4*>(xp + (size_t)i * ELEMS);

    // stage scalars (vectorized, disjoint ranges; two ops on lower half)
    if (tid < 128) {
        reinterpret_cast<float4*>(sd)[tid] =
            reinterpret_cast<const float4*>(decay_t + (size_t)row * T_SZ)[tid];
        reinterpret_cast<float4*>(sR)[tid] =
            reinterpret_cast<const float4*>(Rst + b * T_SZ)[tid];
    } else {
        const int i = tid - 128;
        reinterpret_cast<float4*>(sM)[i] =
            reinterpret_cast<const float4*>(Mst + b * T_SZ)[i];
    }
    const float4 lw = *reinterpret_cast<const float4*>(ln_w + r * D_SZ + c0);
    const float4 lb = *reinterpret_cast<const float4*>(ln_b + r * D_SZ + c0);
    __syncthreads();

    // local inclusive scan; decays kept in registers for reuse
    float4 v[CLEN2];
    float  d_[CLEN2];
    float4 S = make_float4(0.f, 0.f, 0.f, 0.f);
    float  P = 1.f;
#pragma unroll
    for (int i = 0; i < CLEN2; ++i) {
        const int   t = t0 + i;
        const float M = sM[t], R = sR[t], d = sd[t];
        S.x = fmaf(S.x, d, fmaf(fmaf(xv[i].x, R, -M), lw.x, lb.x));
        S.y = fmaf(S.y, d, fmaf(fmaf(xv[i].y, R, -M), lw.y, lb.y));
        S.z = fmaf(S.z, d, fmaf(fmaf(xv[i].z, R, -M), lw.z, lb.z));
        S.w = fmaf(S.w, d, fmaf(fmaf(xv[i].w, R, -M), lw.w, lb.w));
        d_[i] = d;
        P *= d;
        v[i] = S;
    }

    sS[k][cg] = S;
    if (cg == 0) sP[k] = P;
    __syncthreads();

    // level 1: fold within group g over chunks [8g, k)  (depth <= 7)
    const int g  = k >> 3;
    const int g0 = g << 3;
    float4 L = make_float4(0.f, 0.f, 0.f, 0.f);
    float  Q = 1.f;
    for (int j = g0; j < k; ++j) {
        const float  Pj = sP[j];
        const float4 Sj = sS[j][cg];
        L.x = fmaf(Pj, L.x, Sj.x);
        L.y = fmaf(Pj, L.y, Sj.y);
        L.z = fmaf(Pj, L.z, Sj.z);
        L.w = fmaf(Pj, L.w, Sj.w);
        Q *= Pj;
    }
    // group aggregates from the last chunk of each group
    if ((k & 7) == 7) {
        float4 GS;
        GS.x = fmaf(P, L.x, S.x);
        GS.y = fmaf(P, L.y, S.y);
        GS.z = fmaf(P, L.z, S.z);
        GS.w = fmaf(P, L.w, S.w);
        sGS[g][cg] = GS;
        if (cg == 0) sGP[g] = Q * P;
    }
    __syncthreads();

    // level 2: fold group aggregates over h < g  (depth <= 7)
    float4 CG = make_float4(0.f, 0.f, 0.f, 0.f);
    for (int h = 0; h < g; ++h) {
        const float  Ph = sGP[h];
        const float4 Sh = sGS[h][cg];
        CG.x = fmaf(Ph, CG.x, Sh.x);
        CG.y = fmaf(Ph, CG.y, Sh.y);
        CG.z = fmaf(Ph, CG.z, Sh.z);
        CG.w = fmaf(Ph, CG.w, Sh.w);
    }
    float4 C;
    C.x = fmaf(Q, CG.x, L.x);
    C.y = fmaf(Q, CG.y, L.y);
    C.z = fmaf(Q, CG.z, L.z);
    C.w = fmaf(Q, CG.w, L.w);

    // apply carry and write
    float* op = out + ((size_t)(b * T_SZ + t0) * D_SZ + r) * D_SZ + c0;
    float rp = 1.f;
#pragma unroll
    for (int i = 0; i < CLEN2; ++i) {
        rp *= d_[i];
        float4 o;
        o.x = fmaf(rp, C.x, v[i].x);
        o.y = fmaf(rp, C.y, v[i].y);
        o.z = fmaf(rp, C.z, v[i].z);
        o.w = fmaf(rp, C.w, v[i].w);
        *reinterpret_cast<float4*>(op + (size_t)i * ELEMS) = o;
    }
}

extern "C" void kernel_launch(void* const* d_in, const int* in_sizes, int n_in,
                              void* d_out, int out_size, void* d_ws, size_t ws_size,
                              hipStream_t stream) {
    const float* x     = (const float*)d_in[0];
    const float* log_A = (const float*)d_in[1];
    const float* dt_w  = (const float*)d_in[2];
    const float* dt_b  = (const float*)d_in[3];
    const float* ln_w  = (const float*)d_in[4];
    const float* ln_b  = (const float*)d_in[5];
    float* out     = (float*)d_out;
    float* decay_t = (float*)d_ws;
    float* Mst     = (float*)((char*)d_ws + M_OFF);
    float* Rst     = (float*)((char*)d_ws + R_OFF);

    ln_dt_kernel<<<B_SZ * T_SZ, 256, 0, stream>>>(
        x, log_A, dt_w, dt_b, ln_w, ln_b, decay_t, Mst, Rst);

    scan_hfold_kernel<<<B_SZ * D_SZ * 4, 256, 0, stream>>>(
        x, Mst, Rst, decay_t, ln_w, ln_b, out);
}

// Round 15
// 20.529 us; speedup vs baseline: 1.2491x; 1.2491x over previous
//
#include <hip/hip_runtime.h>
#include <math.h>

#define B_SZ 2
#define T_SZ 512
#define D_SZ 64
#define ELEMS 4096            // D*D

typedef float f32x4 __attribute__((ext_vector_type(4)));

// K2 geometry (R12, best): 256 blocks = (b, r, col-half). 512 threads =
// 64 chunks x 8 float4 col-groups. CLEN2=8. Hierarchical 8x8 carry fold.
#define NCH2 64
#define CLEN2 8               // NCH2*CLEN2 == T_SZ
#define NCG  8                // col-groups per block (8 x float4 = 32 cols)

// ws layout: decay_t [B][D][T] at 0 (256 KB); M=mu*rs [B*T]; R=rs [B*T]
#define DECAY_BYTES ((size_t)B_SZ * D_SZ * T_SZ * 4)
#define M_OFF   DECAY_BYTES
#define R_OFF   (DECAY_BYTES + (size_t)B_SZ * T_SZ * 4)

// Kernel 1 (proven): per-(b,t) LN stats + row-dot + decay.
__global__ __launch_bounds__(256) void ln_dt_kernel(
    const float* __restrict__ x, const float* __restrict__ log_A,
    const float* __restrict__ dt_w, const float* __restrict__ dt_b,
    const float* __restrict__ ln_w, const float* __restrict__ ln_b,
    float* __restrict__ decay_t, float* __restrict__ Mst, float* __restrict__ Rst)
{
    const int bt  = blockIdx.x;
    const int tid = threadIdx.x;
    const size_t base = (size_t)bt * ELEMS;

    float4 v[4];
    float sum = 0.f, sumsq = 0.f;
    const float4* xv4 = reinterpret_cast<const float4*>(x + base);
#pragma unroll
    for (int k = 0; k < 4; ++k) {
        v[k] = xv4[tid + 256 * k];
        sum   += v[k].x + v[k].y + v[k].z + v[k].w;
        sumsq += v[k].x * v[k].x + v[k].y * v[k].y + v[k].z * v[k].z + v[k].w * v[k].w;
    }

    __shared__ float red0[4], red1[4];
#pragma unroll
    for (int off = 32; off; off >>= 1) {
        sum   += __shfl_down(sum, off);
        sumsq += __shfl_down(sumsq, off);
    }
    const int wave = tid >> 6;
    if ((tid & 63) == 0) { red0[wave] = sum; red1[wave] = sumsq; }
    __syncthreads();
    sum   = red0[0] + red0[1] + red0[2] + red0[3];
    sumsq = red1[0] + red1[1] + red1[2] + red1[3];

    const float mu = sum * (1.f / ELEMS);
    const float var = sumsq * (1.f / ELEMS) - mu * mu;
    const float rs = rsqrtf(var + 1e-5f);

    const float4* w4p = reinterpret_cast<const float4*>(ln_w);
    const float4* b4p = reinterpret_cast<const float4*>(ln_b);
    const float4* dw4 = reinterpret_cast<const float4*>(dt_w);
    float dot[4] = {0.f, 0.f, 0.f, 0.f};
#pragma unroll
    for (int k = 0; k < 4; ++k) {
        const int f = tid + 256 * k;
        float4 w4 = w4p[f];
        float4 b4 = b4p[f];
        float4 xn;
        xn.x = (v[k].x - mu) * rs * w4.x + b4.x;
        xn.y = (v[k].y - mu) * rs * w4.y + b4.y;
        xn.z = (v[k].z - mu) * rs * w4.z + b4.z;
        xn.w = (v[k].w - mu) * rs * w4.w + b4.w;
        float4 wv = dw4[f & 15];
        dot[k] += xn.x * wv.x + xn.y * wv.y + xn.z * wv.z + xn.w * wv.w;
    }

#pragma unroll
    for (int m = 1; m <= 8; m <<= 1) {
#pragma unroll
        for (int k = 0; k < 4; ++k) dot[k] += __shfl_xor(dot[k], m);
    }

    if (tid == 0) { Mst[bt] = mu * rs; Rst[bt] = rs; }

    if ((tid & 15) == 0) {
        const int m = tid >> 4;
        const float db = dt_b[0];
        const int b = bt >> 9;
        const int t = bt & (T_SZ - 1);
#pragma unroll
        for (int k = 0; k < 4; ++k) {
            const int r = m + 16 * k;
            const float z = dot[k] + db;
            const float dt = (z > 20.f) ? z : log1pf(expf(z));
            const float A = -expf(log_A[r]);
            decay_t[((size_t)(b * D_SZ + r)) * T_SZ + t] = expf(dt * A);
        }
    }
}

// Kernel 2: R12 structure + hoisted loads + register decays + nt stores.
__global__ __launch_bounds__(512, 2) void scan_hfold_kernel(
    const float* __restrict__ x,
    const float* __restrict__ Mst, const float* __restrict__ Rst,
    const float* __restrict__ decay_t,
    const float* __restrict__ ln_w, const float* __restrict__ ln_b,
    float* __restrict__ out)
{
    const int tid = threadIdx.x;
    const int cg  = tid & (NCG - 1);      // 0..7
    const int k   = tid >> 3;             // chunk 0..63
    const int ch  = blockIdx.x & 1;       // col-half
    const int row = blockIdx.x >> 1;      // (b*64 + r)
    const int b   = row >> 6;
    const int r   = row & 63;
    const int t0  = k * CLEN2;
    const int c0  = ch * 32 + cg * 4;

    __shared__ float  sd[T_SZ];
    __shared__ float  sM[T_SZ];
    __shared__ float  sR[T_SZ];
    __shared__ float4 sS[NCH2][NCG];
    __shared__ float  sP[NCH2];
    __shared__ float4 sGS[8][NCG];
    __shared__ float  sGP[8];

    // hoisted x tile loads (8 independent 128B-segment loads in flight)
    const float* xp = x + ((size_t)(b * T_SZ + t0) * D_SZ + r) * D_SZ + c0;
    float4 xv[CLEN2];
#pragma unroll
    for (int i = 0; i < CLEN2; ++i)
        xv[i] = *reinterpret_cast<const float4*>(xp + (size_t)i * ELEMS);

    // stage scalars (vectorized, disjoint thread ranges)
    if (tid < 128) {
        reinterpret_cast<float4*>(sd)[tid] =
            reinterpret_cast<const float4*>(decay_t + (size_t)row * T_SZ)[tid];
    } else if (tid < 256) {
        const int i = tid - 128;
        reinterpret_cast<float4*>(sM)[i] =
            reinterpret_cast<const float4*>(Mst + b * T_SZ)[i];
    } else if (tid < 384) {
        const int i = tid - 256;
        reinterpret_cast<float4*>(sR)[i] =
            reinterpret_cast<const float4*>(Rst + b * T_SZ)[i];
    }
    const float4 lw = *reinterpret_cast<const float4*>(ln_w + r * D_SZ + c0);
    const float4 lb = *reinterpret_cast<const float4*>(ln_b + r * D_SZ + c0);
    __syncthreads();

    // local inclusive scan; decays kept in registers for the apply chain
    float4 v[CLEN2];
    float  d_[CLEN2];
    float4 S = make_float4(0.f, 0.f, 0.f, 0.f);
    float  P = 1.f;
#pragma unroll
    for (int i = 0; i < CLEN2; ++i) {
        const int   t = t0 + i;
        const float M = sM[t], R = sR[t], d = sd[t];
        S.x = fmaf(S.x, d, fmaf(fmaf(xv[i].x, R, -M), lw.x, lb.x));
        S.y = fmaf(S.y, d, fmaf(fmaf(xv[i].y, R, -M), lw.y, lb.y));
        S.z = fmaf(S.z, d, fmaf(fmaf(xv[i].z, R, -M), lw.z, lb.z));
        S.w = fmaf(S.w, d, fmaf(fmaf(xv[i].w, R, -M), lw.w, lb.w));
        d_[i] = d;
        P *= d;
        v[i] = S;
    }

    sS[k][cg] = S;
    if (cg == 0) sP[k] = P;
    __syncthreads();

    // level 1: fold within group g over chunks [8g, k)  (depth <= 7)
    const int g  = k >> 3;
    const int g0 = g << 3;
    float4 L = make_float4(0.f, 0.f, 0.f, 0.f);
    float  Q = 1.f;
    for (int j = g0; j < k; ++j) {
        const float  Pj = sP[j];
        const float4 Sj = sS[j][cg];
        L.x = fmaf(Pj, L.x, Sj.x);
        L.y = fmaf(Pj, L.y, Sj.y);
        L.z = fmaf(Pj, L.z, Sj.z);
        L.w = fmaf(Pj, L.w, Sj.w);
        Q *= Pj;
    }
    if ((k & 7) == 7) {
        float4 GS;
        GS.x = fmaf(P, L.x, S.x);
        GS.y = fmaf(P, L.y, S.y);
        GS.z = fmaf(P, L.z, S.z);
        GS.w = fmaf(P, L.w, S.w);
        sGS[g][cg] = GS;
        if (cg == 0) sGP[g] = Q * P;
    }
    __syncthreads();

    // level 2: fold group aggregates over h < g  (depth <= 7)
    float4 CG = make_float4(0.f, 0.f, 0.f, 0.f);
    for (int h = 0; h < g; ++h) {
        const float  Ph = sGP[h];
        const float4 Sh = sGS[h][cg];
        CG.x = fmaf(Ph, CG.x, Sh.x);
        CG.y = fmaf(Ph, CG.y, Sh.y);
        CG.z = fmaf(Ph, CG.z, Sh.z);
        CG.w = fmaf(Ph, CG.w, Sh.w);
    }
    float4 C;
    C.x = fmaf(Q, CG.x, L.x);
    C.y = fmaf(Q, CG.y, L.y);
    C.z = fmaf(Q, CG.z, L.z);
    C.w = fmaf(Q, CG.w, L.w);

    // apply carry and write with non-temporal stores (out never re-read)
    float* op = out + ((size_t)(b * T_SZ + t0) * D_SZ + r) * D_SZ + c0;
    float rp = 1.f;
#pragma unroll
    for (int i = 0; i < CLEN2; ++i) {
        rp *= d_[i];
        f32x4 o;
        o.x = fmaf(rp, C.x, v[i].x);
        o.y = fmaf(rp, C.y, v[i].y);
        o.z = fmaf(rp, C.z, v[i].z);
        o.w = fmaf(rp, C.w, v[i].w);
        __builtin_nontemporal_store(o, reinterpret_cast<f32x4*>(op + (size_t)i * ELEMS));
    }
}

extern "C" void kernel_launch(void* const* d_in, const int* in_sizes, int n_in,
                              void* d_out, int out_size, void* d_ws, size_t ws_size,
                              hipStream_t stream) {
    const float* x     = (const float*)d_in[0];
    const float* log_A = (const float*)d_in[1];
    const float* dt_w  = (const float*)d_in[2];
    const float* dt_b  = (const float*)d_in[3];
    const float* ln_w  = (const float*)d_in[4];
    const float* ln_b  = (const float*)d_in[5];
    float* out     = (float*)d_out;
    float* decay_t = (float*)d_ws;
    float* Mst     = (float*)((char*)d_ws + M_OFF);
    float* Rst     = (float*)((char*)d_ws + R_OFF);

    ln_dt_kernel<<<B_SZ * T_SZ, 256, 0, stream>>>(
        x, log_A, dt_w, dt_b, ln_w, ln_b, decay_t, Mst, Rst);

    scan_hfold_kernel<<<B_SZ * D_SZ * 2, 512, 0, stream>>>(
        x, Mst, Rst, decay_t, ln_w, ln_b, out);
}

// Round 16
// 20.480 us; speedup vs baseline: 1.2521x; 1.0024x over previous
//
#include <hip/hip_runtime.h>
#include <math.h>

#define B_SZ 2
#define T_SZ 512
#define D_SZ 64
#define ELEMS 4096            // D*D

typedef float f32x4 __attribute__((ext_vector_type(4)));

// K2 geometry: 256 blocks = (b, r, col-half). 512 threads = 64 chunks x 8
// float4 col-groups. CLEN2=8. Hierarchical 8x8 carry fold. Per-chunk scalars
// (d, M, R) loaded straight to registers (no LDS staging, single barrier).
#define NCH2 64
#define CLEN2 8               // NCH2*CLEN2 == T_SZ
#define NCG  8                // col-groups per block (8 x float4 = 32 cols)

// ws layout: decay_t [B][D][T] at 0 (256 KB); M=mu*rs [B*T]; R=rs [B*T]
#define DECAY_BYTES ((size_t)B_SZ * D_SZ * T_SZ * 4)
#define M_OFF   DECAY_BYTES
#define R_OFF   (DECAY_BYTES + (size_t)B_SZ * T_SZ * 4)

// Kernel 1 (proven): per-(b,t) LN stats + row-dot + decay.
__global__ __launch_bounds__(256) void ln_dt_kernel(
    const float* __restrict__ x, const float* __restrict__ log_A,
    const float* __restrict__ dt_w, const float* __restrict__ dt_b,
    const float* __restrict__ ln_w, const float* __restrict__ ln_b,
    float* __restrict__ decay_t, float* __restrict__ Mst, float* __restrict__ Rst)
{
    const int bt  = blockIdx.x;
    const int tid = threadIdx.x;
    const size_t base = (size_t)bt * ELEMS;

    float4 v[4];
    float sum = 0.f, sumsq = 0.f;
    const float4* xv4 = reinterpret_cast<const float4*>(x + base);
#pragma unroll
    for (int k = 0; k < 4; ++k) {
        v[k] = xv4[tid + 256 * k];
        sum   += v[k].x + v[k].y + v[k].z + v[k].w;
        sumsq += v[k].x * v[k].x + v[k].y * v[k].y + v[k].z * v[k].z + v[k].w * v[k].w;
    }

    __shared__ float red0[4], red1[4];
#pragma unroll
    for (int off = 32; off; off >>= 1) {
        sum   += __shfl_down(sum, off);
        sumsq += __shfl_down(sumsq, off);
    }
    const int wave = tid >> 6;
    if ((tid & 63) == 0) { red0[wave] = sum; red1[wave] = sumsq; }
    __syncthreads();
    sum   = red0[0] + red0[1] + red0[2] + red0[3];
    sumsq = red1[0] + red1[1] + red1[2] + red1[3];

    const float mu = sum * (1.f / ELEMS);
    const float var = sumsq * (1.f / ELEMS) - mu * mu;
    const float rs = rsqrtf(var + 1e-5f);

    const float4* w4p = reinterpret_cast<const float4*>(ln_w);
    const float4* b4p = reinterpret_cast<const float4*>(ln_b);
    const float4* dw4 = reinterpret_cast<const float4*>(dt_w);
    float dot[4] = {0.f, 0.f, 0.f, 0.f};
#pragma unroll
    for (int k = 0; k < 4; ++k) {
        const int f = tid + 256 * k;
        float4 w4 = w4p[f];
        float4 b4 = b4p[f];
        float4 xn;
        xn.x = (v[k].x - mu) * rs * w4.x + b4.x;
        xn.y = (v[k].y - mu) * rs * w4.y + b4.y;
        xn.z = (v[k].z - mu) * rs * w4.z + b4.z;
        xn.w = (v[k].w - mu) * rs * w4.w + b4.w;
        float4 wv = dw4[f & 15];
        dot[k] += xn.x * wv.x + xn.y * wv.y + xn.z * wv.z + xn.w * wv.w;
    }

#pragma unroll
    for (int m = 1; m <= 8; m <<= 1) {
#pragma unroll
        for (int k = 0; k < 4; ++k) dot[k] += __shfl_xor(dot[k], m);
    }

    if (tid == 0) { Mst[bt] = mu * rs; Rst[bt] = rs; }

    if ((tid & 15) == 0) {
        const int m = tid >> 4;
        const float db = dt_b[0];
        const int b = bt >> 9;
        const int t = bt & (T_SZ - 1);
#pragma unroll
        for (int k = 0; k < 4; ++k) {
            const int r = m + 16 * k;
            const float z = dot[k] + db;
            const float dt = (z > 20.f) ? z : log1pf(expf(z));
            const float A = -expf(log_A[r]);
            decay_t[((size_t)(b * D_SZ + r)) * T_SZ + t] = expf(dt * A);
        }
    }
}

// Kernel 2: R15 structure, but per-chunk scalars in registers (one barrier).
__global__ __launch_bounds__(512, 2) void scan_hfold_kernel(
    const float* __restrict__ x,
    const float* __restrict__ Mst, const float* __restrict__ Rst,
    const float* __restrict__ decay_t,
    const float* __restrict__ ln_w, const float* __restrict__ ln_b,
    float* __restrict__ out)
{
    const int tid = threadIdx.x;
    const int cg  = tid & (NCG - 1);      // 0..7
    const int k   = tid >> 3;             // chunk 0..63
    const int ch  = blockIdx.x & 1;       // col-half
    const int row = blockIdx.x >> 1;      // (b*64 + r)
    const int b   = row >> 6;
    const int r   = row & 63;
    const int t0  = k * CLEN2;
    const int c0  = ch * 32 + cg * 4;

    __shared__ float4 sS[NCH2][NCG];
    __shared__ float  sP[NCH2];
    __shared__ float4 sGS[8][NCG];
    __shared__ float  sGP[8];

    // hoisted x tile loads (8 independent 128B-segment loads in flight)
    const float* xp = x + ((size_t)(b * T_SZ + t0) * D_SZ + r) * D_SZ + c0;
    float4 xv[CLEN2];
#pragma unroll
    for (int i = 0; i < CLEN2; ++i)
        xv[i] = *reinterpret_cast<const float4*>(xp + (size_t)i * ELEMS);

    // per-chunk scalars straight to registers (L1-broadcast across 8 cg's)
    float4 dv[2], Mv[2], Rv[2];
    {
        const float4* dp = reinterpret_cast<const float4*>(decay_t + (size_t)row * T_SZ + t0);
        const float4* Mp = reinterpret_cast<const float4*>(Mst + b * T_SZ + t0);
        const float4* Rp = reinterpret_cast<const float4*>(Rst + b * T_SZ + t0);
        dv[0] = dp[0]; dv[1] = dp[1];
        Mv[0] = Mp[0]; Mv[1] = Mp[1];
        Rv[0] = Rp[0]; Rv[1] = Rp[1];
    }
    const float* df = reinterpret_cast<const float*>(dv);
    const float* Mf = reinterpret_cast<const float*>(Mv);
    const float* Rf = reinterpret_cast<const float*>(Rv);

    const float4 lw = *reinterpret_cast<const float4*>(ln_w + r * D_SZ + c0);
    const float4 lb = *reinterpret_cast<const float4*>(ln_b + r * D_SZ + c0);

    // local inclusive scan
    float4 v[CLEN2];
    float4 S = make_float4(0.f, 0.f, 0.f, 0.f);
    float  P = 1.f;
#pragma unroll
    for (int i = 0; i < CLEN2; ++i) {
        const float M = Mf[i], R = Rf[i], d = df[i];
        S.x = fmaf(S.x, d, fmaf(fmaf(xv[i].x, R, -M), lw.x, lb.x));
        S.y = fmaf(S.y, d, fmaf(fmaf(xv[i].y, R, -M), lw.y, lb.y));
        S.z = fmaf(S.z, d, fmaf(fmaf(xv[i].z, R, -M), lw.z, lb.z));
        S.w = fmaf(S.w, d, fmaf(fmaf(xv[i].w, R, -M), lw.w, lb.w));
        P *= d;
        v[i] = S;
    }

    sS[k][cg] = S;
    if (cg == 0) sP[k] = P;
    __syncthreads();

    // level 1: fold within group g over chunks [8g, k)  (depth <= 7)
    const int g  = k >> 3;
    const int g0 = g << 3;
    float4 L = make_float4(0.f, 0.f, 0.f, 0.f);
    float  Q = 1.f;
    for (int j = g0; j < k; ++j) {
        const float  Pj = sP[j];
        const float4 Sj = sS[j][cg];
        L.x = fmaf(Pj, L.x, Sj.x);
        L.y = fmaf(Pj, L.y, Sj.y);
        L.z = fmaf(Pj, L.z, Sj.z);
        L.w = fmaf(Pj, L.w, Sj.w);
        Q *= Pj;
    }
    if ((k & 7) == 7) {
        float4 GS;
        GS.x = fmaf(P, L.x, S.x);
        GS.y = fmaf(P, L.y, S.y);
        GS.z = fmaf(P, L.z, S.z);
        GS.w = fmaf(P, L.w, S.w);
        sGS[g][cg] = GS;
        if (cg == 0) sGP[g] = Q * P;
    }
    __syncthreads();

    // level 2: fold group aggregates over h < g  (depth <= 7)
    float4 CG = make_float4(0.f, 0.f, 0.f, 0.f);
    for (int h = 0; h < g; ++h) {
        const float  Ph = sGP[h];
        const float4 Sh = sGS[h][cg];
        CG.x = fmaf(Ph, CG.x, Sh.x);
        CG.y = fmaf(Ph, CG.y, Sh.y);
        CG.z = fmaf(Ph, CG.z, Sh.z);
        CG.w = fmaf(Ph, CG.w, Sh.w);
    }
    float4 C;
    C.x = fmaf(Q, CG.x, L.x);
    C.y = fmaf(Q, CG.y, L.y);
    C.z = fmaf(Q, CG.z, L.z);
    C.w = fmaf(Q, CG.w, L.w);

    // apply carry and write with non-temporal stores (out never re-read)
    float* op = out + ((size_t)(b * T_SZ + t0) * D_SZ + r) * D_SZ + c0;
    float rp = 1.f;
#pragma unroll
    for (int i = 0; i < CLEN2; ++i) {
        rp *= df[i];
        f32x4 o;
        o.x = fmaf(rp, C.x, v[i].x);
        o.y = fmaf(rp, C.y, v[i].y);
        o.z = fmaf(rp, C.z, v[i].z);
        o.w = fmaf(rp, C.w, v[i].w);
        __builtin_nontemporal_store(o, reinterpret_cast<f32x4*>(op + (size_t)i * ELEMS));
    }
}

extern "C" void kernel_launch(void* const* d_in, const int* in_sizes, int n_in,
                              void* d_out, int out_size, void* d_ws, size_t ws_size,
                              hipStream_t stream) {
    const float* x     = (const float*)d_in[0];
    const float* log_A = (const float*)d_in[1];
    const float* dt_w  = (const float*)d_in[2];
    const float* dt_b  = (const float*)d_in[3];
    const float* ln_w  = (const float*)d_in[4];
    const float* ln_b  = (const float*)d_in[5];
    float* out     = (float*)d_out;
    float* decay_t = (float*)d_ws;
    float* Mst     = (float*)((char*)d_ws + M_OFF);
    float* Rst     = (float*)((char*)d_ws + R_OFF);

    ln_dt_kernel<<<B_SZ * T_SZ, 256, 0, stream>>>(
        x, log_A, dt_w, dt_b, ln_w, ln_b, decay_t, Mst, Rst);

    scan_hfold_kernel<<<B_SZ * D_SZ * 2, 512, 0, stream>>>(
        x, Mst, Rst, decay_t, ln_w, ln_b, out);
}